// Round 5
// baseline (223.660 us; speedup 1.0000x reference)
//
#include <hip/hip_runtime.h>
#include <hip/hip_bf16.h>

#define N_NODES 50000
#define N_EDGES 800000
#define IN_F 128
#define OUT_F 128
#define TOPK 32
#define MAXDEG 64    // Poisson(16) tail at 64 ~1e-15; guarded below
#define NBINS 8
#define PSZ 6250     // nodes per dst-partition (8 * 6250 = 50000 exactly)
#define BINCAP 512   // per-block LDS bin capacity (mean 256; P(ovf) ~ e^-99)
#define BCAP 105000  // per-bucket global capacity (mean 100000, sigma ~300)

typedef __attribute__((ext_vector_type(8))) short short8;
typedef __attribute__((ext_vector_type(4))) float f32x4;

static __device__ inline unsigned short f2bf(float x) {
    __hip_bfloat16 h = __float2bfloat16(x);
    return *reinterpret_cast<unsigned short*>(&h);
}

// ---------------------------------------------------------------------------
// Kernel A: one coalesced pass over the edge list; LDS-bin records by
// dst-partition; flush each bin as a contiguous run into its global bucket.
// Blocks 0/1 additionally transpose Ws/Wn -> bf16 WT[col][k] (32 KB each),
// removing the per-block B-tile LDS staging from the GEMM kernel entirely.
// rec = (dst_local << 16) | src   (dst_local < 6250, src < 50000 < 65536)
// ---------------------------------------------------------------------------
__global__ __launch_bounds__(256) void bin_kernel(
    const int* __restrict__ src, const int* __restrict__ dst,
    unsigned* __restrict__ staged, int* __restrict__ gtail,
    int* __restrict__ deg_pad, unsigned short* __restrict__ esrc_pad,
    const float* __restrict__ Ws, const float* __restrict__ Wn,
    unsigned short* __restrict__ WsT, unsigned short* __restrict__ WnT, int E) {
    __shared__ unsigned lbin[NBINS][BINCAP];   // 16 KB
    __shared__ int lcnt[NBINS];
    __shared__ int lbase[NBINS];
    int t = threadIdx.x;

    // ---- weight transpose (blocks 0,1): WT[c*128+k] = bf16(W[k*128+c]) ----
    if (blockIdx.x < 2) {
        const float* W = (blockIdx.x == 0) ? Ws : Wn;
        unsigned short* WT = (blockIdx.x == 0) ? WsT : WnT;
        for (int i = t; i < IN_F * OUT_F; i += 256) {
            int k = i >> 7, c = i & 127;          // read coalesced
            WT[c * IN_F + k] = f2bf(W[i]);        // tiny scattered writes (32KB)
        }
    }

    if (t < NBINS) lcnt[t] = 0;
    __syncthreads();
    int base = blockIdx.x * 2048;
#pragma unroll
    for (int q = 0; q < 8; ++q) {
        int e = base + q * 256 + t;
        if (e < E) {
            int d = dst[e];
            int s = src[e];
            int b = d / PSZ;
            unsigned rec = ((unsigned)(d - b * PSZ) << 16) | (unsigned)s;
            int idx = atomicAdd(&lcnt[b], 1);
            if (idx < BINCAP) lbin[b][idx] = rec;
            else {  // ~impossible; keep correctness under any data
                int r = atomicAdd(&deg_pad[d << 4], 1);
                if (r < MAXDEG) esrc_pad[d * MAXDEG + r] = (unsigned short)s;
            }
        }
    }
    __syncthreads();
    if (t < NBINS) {
        int c = min(lcnt[t], BINCAP);
        lcnt[t] = c;
        lbase[t] = atomicAdd(&gtail[t], c);
    }
    __syncthreads();
    for (int b = 0; b < NBINS; ++b) {
        int c = lcnt[b];
        int bb = lbase[b];
        unsigned* gb = staged + (size_t)b * BCAP;
        for (int i = t; i < c; i += 256) {
            if (bb + i < BCAP) gb[bb + i] = lbin[b][i];
            else {  // bucket overflow fallback (P ~ 0): direct scatter
                unsigned rec = lbin[b][i];
                int d = b * PSZ + (int)(rec >> 16);
                int r = atomicAdd(&deg_pad[d << 4], 1);
                if (r < MAXDEG) esrc_pad[d * MAXDEG + r] = (unsigned short)(rec & 0xffffu);
            }
        }
    }
}

// ---------------------------------------------------------------------------
// Kernel B (FUSED): bucket-drain scatter prologue + TWO MFMA GEMMs.
// B-fragments load DIRECTLY from pre-transposed global WT (L2-resident 32KB)
// -> no B LDS tile -> LDS = XSL only (38.9KB) -> 4 blocks/CU, 16 waves/CU,
// and all 782 blocks co-resident (drain fully temporally concentrated).
//   blocks [0, GEMB):      out  = feat @ Ws + b        (no LDS use)
//   blocks [GEMB, 2*GEMB): y_bf = x_sparse @ Wn        (A built in LDS)
// ---------------------------------------------------------------------------
#define GEMB ((N_NODES + 127) / 128)   // 391
#define NBLK (2 * GEMB)                // 782
#define XS_PAD 152
__global__ __launch_bounds__(256) void gemm2_scatter_kernel(
    const float* __restrict__ feat, const unsigned short* __restrict__ WsT,
    const float* __restrict__ bias, float* __restrict__ out,
    const float* __restrict__ vals, const int* __restrict__ topk_idx,
    const unsigned short* __restrict__ WnT, unsigned short* __restrict__ y_bf,
    const unsigned* __restrict__ staged, const int* __restrict__ gtail,
    int* __restrict__ deg_pad, unsigned short* __restrict__ esrc_pad,
    int n) {
    __shared__ unsigned short XSL[128 * XS_PAD];   // 38.9 KB A-tile (x_sparse)
    int t = threadIdx.x;

    // ---- scatter prologue: drain my partition's bucket slice ----
    {
        int p   = blockIdx.x & 7;
        int gi  = blockIdx.x >> 3;
        int nbg = (NBLK - p + 7) >> 3;          // blocks in my group (97/98)
        int cnt = min(gtail[p], BCAP);
        int chunk = (cnt + nbg - 1) / nbg;
        int lo = gi * chunk;
        int hi = min(lo + chunk, cnt);
        const unsigned* sb = staged + (size_t)p * BCAP;
        for (int i = lo + t; i < hi; i += 256) {
            unsigned rec = sb[i];
            int d = p * PSZ + (int)(rec >> 16);
            int r = atomicAdd(&deg_pad[d << 4], 1);
            if (r < MAXDEG)
                esrc_pad[d * MAXDEG + r] = (unsigned short)(rec & 0xffffu);
        }
    }

    bool self = (blockIdx.x < GEMB);
    int bx = self ? blockIdx.x : (blockIdx.x - GEMB);
    int rowbase_blk = bx * 128;
    const unsigned short* WT = self ? WsT : WnT;

    if (!self) {
        // ---- build x_sparse tile in LDS ----
        unsigned* xz = (unsigned*)XSL;
#pragma unroll 4
        for (int i = t; i < 128 * XS_PAD / 2; i += 256) xz[i] = 0u;
        __syncthreads();  // zeroing (all threads) before scatter (t<128)
        if (t < 128) {
            int node = rowbase_blk + t;
            if (node < n) {
                int idx[TOPK];
                float v[TOPK];
#pragma unroll
                for (int k = 0; k < TOPK; k += 4) {
                    *(int4*)&idx[k]  = *(const int4*)&topk_idx[(size_t)node * TOPK + k];
                    *(float4*)&v[k]  = *(const float4*)&vals[(size_t)node * TOPK + k];
                }
                unsigned short* rowp = &XSL[t * XS_PAD];
#pragma unroll
                for (int k = 0; k < TOPK; ++k)
                    rowp[idx[k] & 127] = f2bf(v[k]);   // program order => last k wins
            }
        }
        __syncthreads();
    }

    int wave = t >> 6;
    int lane = t & 63;
    int quad = lane >> 4;
    int lq = lane & 15;
    int rowbase = rowbase_blk + wave * 32;
    int r0 = rowbase + lq;
    int r1 = rowbase + 16 + lq;

    f32x4 acc0[8], acc1[8];
#pragma unroll
    for (int i = 0; i < 8; ++i) { acc0[i] = (f32x4){0,0,0,0}; acc1[i] = (f32x4){0,0,0,0}; }

#pragma unroll
    for (int ks = 0; ks < 4; ++ks) {
        int k0 = ks * 32 + quad * 8;
        short8 a0, a1;
        if (self) {
            float4 z = {0.f, 0.f, 0.f, 0.f};
            float4 f00 = (r0 < n) ? *(const float4*)&feat[r0 * IN_F + k0] : z;
            float4 f01 = (r0 < n) ? *(const float4*)&feat[r0 * IN_F + k0 + 4] : z;
            float4 f10 = (r1 < n) ? *(const float4*)&feat[r1 * IN_F + k0] : z;
            float4 f11 = (r1 < n) ? *(const float4*)&feat[r1 * IN_F + k0 + 4] : z;
            union { short8 s; unsigned short u[8]; } ua, ub;
            ua.u[0] = f2bf(f00.x); ua.u[1] = f2bf(f00.y); ua.u[2] = f2bf(f00.z); ua.u[3] = f2bf(f00.w);
            ua.u[4] = f2bf(f01.x); ua.u[5] = f2bf(f01.y); ua.u[6] = f2bf(f01.z); ua.u[7] = f2bf(f01.w);
            ub.u[0] = f2bf(f10.x); ub.u[1] = f2bf(f10.y); ub.u[2] = f2bf(f10.z); ub.u[3] = f2bf(f10.w);
            ub.u[4] = f2bf(f11.x); ub.u[5] = f2bf(f11.y); ub.u[6] = f2bf(f11.z); ub.u[7] = f2bf(f11.w);
            a0 = ua.s; a1 = ub.s;
        } else {
            int lr0 = wave * 32 + lq;
            a0 = *(const short8*)&XSL[lr0 * XS_PAD + k0];
            a1 = *(const short8*)&XSL[(lr0 + 16) * XS_PAD + k0];
        }
#pragma unroll
        for (int nt = 0; nt < 8; ++nt) {
            // B direct from global: 16B contiguous per lane, L2-resident.
            short8 b = *(const short8*)&WT[(nt * 16 + lq) * IN_F + k0];
            acc0[nt] = __builtin_amdgcn_mfma_f32_16x16x32_bf16(a0, b, acc0[nt], 0, 0, 0);
            acc1[nt] = __builtin_amdgcn_mfma_f32_16x16x32_bf16(a1, b, acc1[nt], 0, 0, 0);
        }
    }

    if (self) {
#pragma unroll
        for (int nt = 0; nt < 8; ++nt) {
            int col = nt * 16 + lq;
            float bb = bias[col];
#pragma unroll
            for (int r = 0; r < 4; ++r) {
                int row = rowbase + quad * 4 + r;
                if (row < n) out[row * OUT_F + col] = acc0[nt][r] + bb;
                int row2 = row + 16;
                if (row2 < n) out[row2 * OUT_F + col] = acc1[nt][r] + bb;
            }
        }
    } else {
        // y stored row-major bf16: u32 at [node*64+l] = cols {2l (lo), 2l+1 (hi)}
#pragma unroll
        for (int nt = 0; nt < 8; ++nt) {
            int col = nt * 16 + lq;
#pragma unroll
            for (int r = 0; r < 4; ++r) {
                int row = rowbase + quad * 4 + r;
                if (row < n) y_bf[row * OUT_F + col] = f2bf(acc0[nt][r]);
                int row2 = row + 16;
                if (row2 < n) y_bf[row2 * OUT_F + col] = f2bf(acc1[nt][r]);
            }
        }
    }
}

// ---------------------------------------------------------------------------
// Kernel C (finalizer): out[d] += (1/deg) * sum y[src].  esrc rows are ushort,
// contiguous -> per-wave src batch is ONE coalesced 128B load. No atomics.
// ---------------------------------------------------------------------------
#define AGG_BLOCKS 2048
__global__ __launch_bounds__(256) void agg_out_kernel(
    const int* __restrict__ deg_pad, const unsigned short* __restrict__ esrc_pad,
    const unsigned* __restrict__ y_u, float* __restrict__ out, int n) {
    int wid = (blockIdx.x * 256 + threadIdx.x) >> 6;
    int l = threadIdx.x & 63;
    int nwaves = AGG_BLOCKS * 4;

    for (int d = wid; d < n; d += nwaves) {
        int bc_all = min(deg_pad[d << 4], MAXDEG);
        const unsigned short* row = esrc_pad + d * MAXDEG;
        float2 acc = {0.f, 0.f};
        {
            int bc = bc_all;
            int sv = (bc > 0) ? (int)row[min(l, bc - 1)] : 0;  // one coalesced batch load
            for (int r = 0; r < bc; r += 8) {
                unsigned uu[8];
                float mm[8];
#pragma unroll
                for (int q = 0; q < 8; ++q) {
                    int rr = r + q;
                    mm[q] = (rr < bc) ? 1.f : 0.f;
                    int s = __shfl(sv, min(rr, bc - 1));
                    uu[q] = y_u[s * 64 + l];
                }
#pragma unroll
                for (int q = 0; q < 8; ++q) {
                    acc.x += __uint_as_float(uu[q] << 16) * mm[q];
                    acc.y += __uint_as_float(uu[q] & 0xffff0000u) * mm[q];
                }
            }
        }
        float inv = 1.0f / (float)max(bc_all, 1);
        float2 cur = *(float2*)&out[d * OUT_F + 2 * l];
        cur.x += acc.x * inv;
        cur.y += acc.y * inv;
        *(float2*)&out[d * OUT_F + 2 * l] = cur;
    }
}

// ---------------------------------------------------------------------------
extern "C" void kernel_launch(void* const* d_in, const int* in_sizes, int n_in,
                              void* d_out, int out_size, void* d_ws, size_t ws_size,
                              hipStream_t stream) {
    const float* feat    = (const float*)d_in[0];
    const float* vals    = (const float*)d_in[1];
    const int*   idxs    = (const int*)d_in[2];
    const int*   src     = (const int*)d_in[3];
    const int*   dst     = (const int*)d_in[4];
    const float* W_self  = (const float*)d_in[5];
    const float* b_self  = (const float*)d_in[6];
    const float* W_neigh = (const float*)d_in[7];
    float*       out     = (float*)d_out;

    const int n = N_NODES;
    const int E = N_EDGES;

    // Workspace: [deg_pad n*16 int (3.2MB)][gtail 16 int][y_bf n*128 bf16
    // (12.8MB)][esrc_pad n*64 u16 (6.4MB)][staged 8*105000 u32 (3.36MB)]
    // [WsT 32KB][WnT 32KB]
    char* p = (char*)d_ws;
    int*            deg_pad  = (int*)p;            p += (size_t)n * 16 * sizeof(int);
    int*            gtail    = (int*)p;            p += 16 * sizeof(int);
    unsigned short* y_bf     = (unsigned short*)p; p += (size_t)n * OUT_F * sizeof(unsigned short);
    unsigned short* esrc_pad = (unsigned short*)p; p += (size_t)n * MAXDEG * sizeof(unsigned short);
    unsigned*       staged   = (unsigned*)p;       p += (size_t)NBINS * BCAP * sizeof(unsigned);
    unsigned short* WsT      = (unsigned short*)p; p += (size_t)IN_F * OUT_F * sizeof(unsigned short);
    unsigned short* WnT      = (unsigned short*)p;

    // one memset covers deg_pad + gtail (adjacent)
    hipMemsetAsync(deg_pad, 0, (size_t)n * 16 * sizeof(int) + 16 * sizeof(int), stream);

    bin_kernel<<<(E + 2047) / 2048, 256, 0, stream>>>(
        src, dst, staged, gtail, deg_pad, esrc_pad, W_self, W_neigh, WsT, WnT, E);
    gemm2_scatter_kernel<<<NBLK, 256, 0, stream>>>(
        feat, WsT, b_self, out, vals, idxs, WnT, y_bf,
        staged, gtail, deg_pad, esrc_pad, n);
    agg_out_kernel<<<AGG_BLOCKS, 256, 0, stream>>>(
        deg_pad, esrc_pad, (const unsigned*)y_bf, out, n);
}

// Round 6
// 203.760 us; speedup vs baseline: 1.0977x; 1.0977x over previous
//
#include <hip/hip_runtime.h>
#include <hip/hip_bf16.h>

#define N_NODES 50000
#define N_EDGES 800000
#define IN_F 128
#define OUT_F 128
#define TOPK 32
#define MAXDEG 64     // Poisson(16) tail at 64 ~1e-15; clamped everywhere
#define NB 125        // dst buckets
#define PSZ 400       // nodes per bucket (125 * 400 = 50000 exactly)
#define BINCAP 64     // per-block-per-bucket LDS bin cap (mean ~16.4)
#define BCAP 8000     // per-bucket staged cap (mean 6400, sigma ~80)
#define OVFCAP 65536  // global overflow list (P~0 on random data)

typedef __attribute__((ext_vector_type(8))) short short8;
typedef __attribute__((ext_vector_type(4))) float f32x4;

static __device__ inline unsigned short f2bf(float x) {
    __hip_bfloat16 h = __float2bfloat16(x);
    return *reinterpret_cast<unsigned short*>(&h);
}

// ---------------------------------------------------------------------------
// Kernel A: coalesced edge pass; LDS-bin records by dst-bucket (125 buckets
// of 400 nodes); flush each bin as a contiguous run into its global bucket.
// All global writes are dense runs. Blocks 0/1 also transpose Ws/Wn -> bf16
// WT[col][k].  rec = (dst << 16) | src  (both < 65536).
// Overflows (LDS bin or bucket) go to a global ovf list -> drain handles.
// ---------------------------------------------------------------------------
__global__ __launch_bounds__(256) void bin_kernel(
    const int* __restrict__ src, const int* __restrict__ dst,
    unsigned* __restrict__ staged, int* __restrict__ gtail,
    unsigned* __restrict__ ovf, int* __restrict__ ovf_cnt,
    const float* __restrict__ Ws, const float* __restrict__ Wn,
    unsigned short* __restrict__ WsT, unsigned short* __restrict__ WnT, int E) {
    __shared__ unsigned lbin[NB][BINCAP];   // 32 KB
    __shared__ int lcnt[NB];
    __shared__ int lbase[NB];
    int t = threadIdx.x;

    // ---- weight transpose (blocks 0,1): WT[c*128+k] = bf16(W[k*128+c]) ----
    if (blockIdx.x < 2) {
        const float* W = (blockIdx.x == 0) ? Ws : Wn;
        unsigned short* WT = (blockIdx.x == 0) ? WsT : WnT;
        for (int i = t; i < IN_F * OUT_F; i += 256) {
            int k = i >> 7, c = i & 127;          // read coalesced
            WT[c * IN_F + k] = f2bf(W[i]);        // tiny scattered writes (32KB)
        }
    }

    for (int i = t; i < NB; i += 256) lcnt[i] = 0;
    __syncthreads();

    int e0 = blockIdx.x * 2048 + t * 8;
    if (e0 + 7 < E) {
        int4 s0 = *(const int4*)&src[e0], s1 = *(const int4*)&src[e0 + 4];
        int4 d0 = *(const int4*)&dst[e0], d1 = *(const int4*)&dst[e0 + 4];
        int es[8] = {s0.x, s0.y, s0.z, s0.w, s1.x, s1.y, s1.z, s1.w};
        int ed[8] = {d0.x, d0.y, d0.z, d0.w, d1.x, d1.y, d1.z, d1.w};
#pragma unroll
        for (int q = 0; q < 8; ++q) {
            int b = ed[q] / PSZ;
            unsigned rec = ((unsigned)ed[q] << 16) | (unsigned)es[q];
            int idx = atomicAdd(&lcnt[b], 1);
            if (idx < BINCAP) lbin[b][idx] = rec;
            else { int o = atomicAdd(ovf_cnt, 1); if (o < OVFCAP) ovf[o] = rec; }
        }
    } else {
        for (int q = 0; q < 8; ++q) {
            int e = e0 + q;
            if (e < E) {
                int d = dst[e];
                int b = d / PSZ;
                unsigned rec = ((unsigned)d << 16) | (unsigned)src[e];
                int idx = atomicAdd(&lcnt[b], 1);
                if (idx < BINCAP) lbin[b][idx] = rec;
                else { int o = atomicAdd(ovf_cnt, 1); if (o < OVFCAP) ovf[o] = rec; }
            }
        }
    }
    __syncthreads();
    for (int i = t; i < NB; i += 256) {
        int c = min(lcnt[i], BINCAP);
        lcnt[i] = c;
        lbase[i] = atomicAdd(&gtail[i], c);
    }
    __syncthreads();
    // wave-parallel flush: one bucket per wave iteration, lane==slot
    int lane = t & 63, wv = t >> 6;
    for (int b = wv; b < NB; b += 4) {
        int c = lcnt[b];
        if (lane < c) {
            int pos = lbase[b] + lane;
            unsigned rec = lbin[b][lane];
            if (pos < BCAP) staged[(size_t)b * BCAP + pos] = rec;
            else { int o = atomicAdd(ovf_cnt, 1); if (o < OVFCAP) ovf[o] = rec; }
        }
    }
}

// ---------------------------------------------------------------------------
// Kernel B: counting-sort drain. One block per bucket: rank via LDS atomics,
// build the 400x64 ushort CSR tile IN LDS, then write it (and deg) out as
// dense coalesced blocks. Zero global atomics, zero scattered global stores.
// ---------------------------------------------------------------------------
__global__ __launch_bounds__(256) void drain_kernel(
    const unsigned* __restrict__ staged, const int* __restrict__ gtail,
    const unsigned* __restrict__ ovf, const int* __restrict__ ovf_cnt,
    int* __restrict__ deg, unsigned short* __restrict__ esrc_pad) {
    __shared__ unsigned short csr[PSZ * MAXDEG];   // 50 KB
    __shared__ int cnt[PSZ];                       // 1.6 KB
    int t = threadIdx.x;
    int b = blockIdx.x;
    int d0 = b * PSZ;

    for (int i = t; i < PSZ; i += 256) cnt[i] = 0;
    __syncthreads();

    int c = min(gtail[b], BCAP);
    const unsigned* sb = staged + (size_t)b * BCAP;
    for (int i = t; i < c; i += 256) {
        unsigned rec = sb[i];
        int dloc = (int)(rec >> 16) - d0;
        int r = atomicAdd(&cnt[dloc], 1);
        if (r < MAXDEG) csr[dloc * MAXDEG + r] = (unsigned short)(rec & 0xffffu);
    }
    // overflow list (normally empty)
    int novf = min(*ovf_cnt, OVFCAP);
    for (int i = t; i < novf; i += 256) {
        unsigned rec = ovf[i];
        int dloc = (int)(rec >> 16) - d0;
        if (dloc >= 0 && dloc < PSZ) {
            int r = atomicAdd(&cnt[dloc], 1);
            if (r < MAXDEG) csr[dloc * MAXDEG + r] = (unsigned short)(rec & 0xffffu);
        }
    }
    __syncthreads();

    // dense coalesced writeout: 50 KB CSR tile + 400 degs
    const uint4* cs4 = (const uint4*)csr;
    uint4* dst4 = (uint4*)(esrc_pad + (size_t)d0 * MAXDEG);
    for (int i = t; i < PSZ * MAXDEG / 8; i += 256) dst4[i] = cs4[i];
    for (int i = t; i < PSZ; i += 256) deg[d0 + i] = cnt[i];
}

// ---------------------------------------------------------------------------
// Kernel C: TWO MFMA GEMMs (round-2 proven structure, no prologue).
//   blocks [0, GEMB):      out  = feat @ Ws + b
//   blocks [GEMB, 2*GEMB): y_bf = x_sparse @ Wn   (A built in LDS from topk)
// BL staged as a straight bf16 copy of precomputed WT (no transpose math).
// ---------------------------------------------------------------------------
#define GEMB ((N_NODES + 127) / 128)   // 391
#define NBLK (2 * GEMB)                // 782
#define BK_PAD 136
#define XS_PAD 152
__global__ __launch_bounds__(256) void gemm2_kernel(
    const float* __restrict__ feat, const unsigned short* __restrict__ WsT,
    const float* __restrict__ bias, float* __restrict__ out,
    const float* __restrict__ vals, const int* __restrict__ topk_idx,
    const unsigned short* __restrict__ WnT, unsigned short* __restrict__ y_bf,
    int n) {
    __shared__ unsigned short BL[128 * BK_PAD];    // 34.8 KB
    __shared__ unsigned short XSL[128 * XS_PAD];   // 38.9 KB
    int t = threadIdx.x;

    bool self = (blockIdx.x < GEMB);
    int bx = self ? blockIdx.x : (blockIdx.x - GEMB);
    int rowbase_blk = bx * 128;
    const unsigned short* WT = self ? WsT : WnT;

    // ---- stage B: BL[col][k] = WT[col*128+k]  (plain 16B-chunk copy) ----
    {
        int col = t >> 1;
        int half = t & 1;
        const short8* s = (const short8*)&WT[col * IN_F + half * 64];
        short8* d = (short8*)&BL[col * BK_PAD + half * 64];
#pragma unroll
        for (int i = 0; i < 8; ++i) d[i] = s[i];
    }

    if (!self) {
        // ---- build x_sparse tile in LDS ----
        unsigned* xz = (unsigned*)XSL;
#pragma unroll 4
        for (int i = t; i < 128 * XS_PAD / 2; i += 256) xz[i] = 0u;
        __syncthreads();  // zeroing (all threads) before scatter (t<128)
        if (t < 128) {
            int node = rowbase_blk + t;
            if (node < n) {
                int idx[TOPK];
                float v[TOPK];
#pragma unroll
                for (int k = 0; k < TOPK; k += 4) {
                    *(int4*)&idx[k]  = *(const int4*)&topk_idx[(size_t)node * TOPK + k];
                    *(float4*)&v[k]  = *(const float4*)&vals[(size_t)node * TOPK + k];
                }
                unsigned short* rowp = &XSL[t * XS_PAD];
#pragma unroll
                for (int k = 0; k < TOPK; ++k)
                    rowp[idx[k] & 127] = f2bf(v[k]);   // program order => last k wins
            }
        }
    }
    __syncthreads();

    int wave = t >> 6;
    int lane = t & 63;
    int quad = lane >> 4;
    int lq = lane & 15;
    int rowbase = rowbase_blk + wave * 32;
    int r0 = rowbase + lq;
    int r1 = rowbase + 16 + lq;

    f32x4 acc0[8], acc1[8];
#pragma unroll
    for (int i = 0; i < 8; ++i) { acc0[i] = (f32x4){0,0,0,0}; acc1[i] = (f32x4){0,0,0,0}; }

#pragma unroll
    for (int ks = 0; ks < 4; ++ks) {
        int k0 = ks * 32 + quad * 8;
        short8 a0, a1;
        if (self) {
            float4 z = {0.f, 0.f, 0.f, 0.f};
            float4 f00 = (r0 < n) ? *(const float4*)&feat[r0 * IN_F + k0] : z;
            float4 f01 = (r0 < n) ? *(const float4*)&feat[r0 * IN_F + k0 + 4] : z;
            float4 f10 = (r1 < n) ? *(const float4*)&feat[r1 * IN_F + k0] : z;
            float4 f11 = (r1 < n) ? *(const float4*)&feat[r1 * IN_F + k0 + 4] : z;
            union { short8 s; unsigned short u[8]; } ua, ub;
            ua.u[0] = f2bf(f00.x); ua.u[1] = f2bf(f00.y); ua.u[2] = f2bf(f00.z); ua.u[3] = f2bf(f00.w);
            ua.u[4] = f2bf(f01.x); ua.u[5] = f2bf(f01.y); ua.u[6] = f2bf(f01.z); ua.u[7] = f2bf(f01.w);
            ub.u[0] = f2bf(f10.x); ub.u[1] = f2bf(f10.y); ub.u[2] = f2bf(f10.z); ub.u[3] = f2bf(f10.w);
            ub.u[4] = f2bf(f11.x); ub.u[5] = f2bf(f11.y); ub.u[6] = f2bf(f11.z); ub.u[7] = f2bf(f11.w);
            a0 = ua.s; a1 = ub.s;
        } else {
            int lr0 = wave * 32 + lq;
            a0 = *(const short8*)&XSL[lr0 * XS_PAD + k0];
            a1 = *(const short8*)&XSL[(lr0 + 16) * XS_PAD + k0];
        }
#pragma unroll
        for (int nt = 0; nt < 8; ++nt) {
            short8 b = *(const short8*)&BL[(nt * 16 + lq) * BK_PAD + k0];
            acc0[nt] = __builtin_amdgcn_mfma_f32_16x16x32_bf16(a0, b, acc0[nt], 0, 0, 0);
            acc1[nt] = __builtin_amdgcn_mfma_f32_16x16x32_bf16(a1, b, acc1[nt], 0, 0, 0);
        }
    }

    if (self) {
#pragma unroll
        for (int nt = 0; nt < 8; ++nt) {
            int col = nt * 16 + lq;
            float bb = bias[col];
#pragma unroll
            for (int r = 0; r < 4; ++r) {
                int row = rowbase + quad * 4 + r;
                if (row < n) out[row * OUT_F + col] = acc0[nt][r] + bb;
                int row2 = row + 16;
                if (row2 < n) out[row2 * OUT_F + col] = acc1[nt][r] + bb;
            }
        }
    } else {
        // y row-major bf16: u32 at [node*64+l] = cols {2l (lo), 2l+1 (hi)}
#pragma unroll
        for (int nt = 0; nt < 8; ++nt) {
            int col = nt * 16 + lq;
#pragma unroll
            for (int r = 0; r < 4; ++r) {
                int row = rowbase + quad * 4 + r;
                if (row < n) y_bf[row * OUT_F + col] = f2bf(acc0[nt][r]);
                int row2 = row + 16;
                if (row2 < n) y_bf[row2 * OUT_F + col] = f2bf(acc1[nt][r]);
            }
        }
    }
}

// ---------------------------------------------------------------------------
// Kernel D (finalizer): out[d] += (1/deg) * sum y[src].  esrc rows are ushort,
// contiguous -> per-wave src batch is ONE coalesced 128B load. No atomics.
// ---------------------------------------------------------------------------
#define AGG_BLOCKS 2048
__global__ __launch_bounds__(256) void agg_out_kernel(
    const int* __restrict__ deg, const unsigned short* __restrict__ esrc_pad,
    const unsigned* __restrict__ y_u, float* __restrict__ out, int n) {
    int wid = (blockIdx.x * 256 + threadIdx.x) >> 6;
    int l = threadIdx.x & 63;
    int nwaves = AGG_BLOCKS * 4;

    for (int d = wid; d < n; d += nwaves) {
        int bc_all = min(deg[d], MAXDEG);
        const unsigned short* row = esrc_pad + (size_t)d * MAXDEG;
        float2 acc = {0.f, 0.f};
        {
            int bc = bc_all;
            int sv = (bc > 0) ? (int)row[min(l, bc - 1)] : 0;  // one coalesced batch load
            for (int r = 0; r < bc; r += 8) {
                unsigned uu[8];
                float mm[8];
#pragma unroll
                for (int q = 0; q < 8; ++q) {
                    int rr = r + q;
                    mm[q] = (rr < bc) ? 1.f : 0.f;
                    int s = __shfl(sv, min(rr, bc - 1));
                    uu[q] = y_u[s * 64 + l];
                }
#pragma unroll
                for (int q = 0; q < 8; ++q) {
                    acc.x += __uint_as_float(uu[q] << 16) * mm[q];
                    acc.y += __uint_as_float(uu[q] & 0xffff0000u) * mm[q];
                }
            }
        }
        float inv = 1.0f / (float)max(bc_all, 1);
        float2 cur = *(float2*)&out[d * OUT_F + 2 * l];
        cur.x += acc.x * inv;
        cur.y += acc.y * inv;
        *(float2*)&out[d * OUT_F + 2 * l] = cur;
    }
}

// ---------------------------------------------------------------------------
extern "C" void kernel_launch(void* const* d_in, const int* in_sizes, int n_in,
                              void* d_out, int out_size, void* d_ws, size_t ws_size,
                              hipStream_t stream) {
    const float* feat    = (const float*)d_in[0];
    const float* vals    = (const float*)d_in[1];
    const int*   idxs    = (const int*)d_in[2];
    const int*   src     = (const int*)d_in[3];
    const int*   dst     = (const int*)d_in[4];
    const float* W_self  = (const float*)d_in[5];
    const float* b_self  = (const float*)d_in[6];
    const float* W_neigh = (const float*)d_in[7];
    float*       out     = (float*)d_out;

    const int n = N_NODES;
    const int E = N_EDGES;

    // Workspace: [gtail 128 int | ovf_cnt at +125][deg n int][y_bf n*128 bf16]
    //            [esrc_pad n*64 u16][staged 125*8000 u32][ovf 64K u32]
    //            [WsT 32KB][WnT 32KB]   total ~24 MB
    char* p = (char*)d_ws;
    int*            gtail    = (int*)p;            p += 128 * sizeof(int);
    int*            ovf_cnt  = gtail + 125;
    int*            deg      = (int*)p;            p += (size_t)n * sizeof(int);
    unsigned short* y_bf     = (unsigned short*)p; p += (size_t)n * OUT_F * sizeof(unsigned short);
    unsigned short* esrc_pad = (unsigned short*)p; p += (size_t)n * MAXDEG * sizeof(unsigned short);
    unsigned*       staged   = (unsigned*)p;       p += (size_t)NB * BCAP * sizeof(unsigned);
    unsigned*       ovf      = (unsigned*)p;       p += (size_t)OVFCAP * sizeof(unsigned);
    unsigned short* WsT      = (unsigned short*)p; p += (size_t)IN_F * OUT_F * sizeof(unsigned short);
    unsigned short* WnT      = (unsigned short*)p;

    hipMemsetAsync(gtail, 0, 128 * sizeof(int), stream);

    bin_kernel<<<(E + 2047) / 2048, 256, 0, stream>>>(
        src, dst, staged, gtail, ovf, ovf_cnt, W_self, W_neigh, WsT, WnT, E);
    drain_kernel<<<NB, 256, 0, stream>>>(
        staged, gtail, ovf, ovf_cnt, deg, esrc_pad);
    gemm2_kernel<<<NBLK, 256, 0, stream>>>(
        feat, WsT, b_self, out, vals, idxs, WnT, y_bf, n);
    agg_out_kernel<<<AGG_BLOCKS, 256, 0, stream>>>(
        deg, esrc_pad, (const unsigned*)y_bf, out, n);
}